// Round 11
// baseline (689.663 us; speedup 1.0000x reference)
//
#include <hip/hip_runtime.h>

#define N_NODES 165888
#define N_EDGES 3317760
#define NBKT 648            // N_NODES >> 8 buckets (256 nodes each)
#define NB 512              // partition blocks
#define EPB (N_EDGES / NB)  // 6480 edges per partition block
#define HSZ (NBKT * NB)     // 331776 counters
#define RNG 20736           // N_NODES / 8 : source-range width (2.65 MB of rows)
#define LN_EPS 1e-5f

typedef _Float16 f16;
typedef _Float16 half8 __attribute__((ext_vector_type(8)));
typedef float f32x4 __attribute__((ext_vector_type(4)));
typedef unsigned long long u64;

__device__ __forceinline__ f32x4 mfma16(half8 a, half8 b, f32x4 c) {
    return __builtin_amdgcn_mfma_f32_16x16x32_f16(a, b, c, 0, 0, 0);
}

// ---------------- radix partition (no global atomics, no contention) ----------------

__global__ __launch_bounds__(256) void k_hist2d(const int* __restrict__ dst,
                                                int* __restrict__ h2) {
    __shared__ int hist[NBKT];
    int t = threadIdx.x, b = blockIdx.x;
    for (int i = t; i < NBKT; i += 256) hist[i] = 0;
    __syncthreads();
    int e0 = b * EPB;
    for (int e = e0 + t; e < e0 + EPB; e += 256)
        atomicAdd(&hist[dst[e] >> 8], 1);
    __syncthreads();
    for (int i = t; i < NBKT; i += 256)
        h2[i * NB + b] = hist[i];
}

__global__ void k_scan1(int* __restrict__ h2, int* __restrict__ bsum) {
    __shared__ int s[1024];
    int t = threadIdx.x;
    int i = blockIdx.x * 1024 + t;
    int own = h2[i];
    s[t] = own;
    __syncthreads();
    for (int off = 1; off < 1024; off <<= 1) {
        int u = (t >= off) ? s[t - off] : 0;
        __syncthreads();
        s[t] += u;
        __syncthreads();
    }
    h2[i] = s[t] - own;
    if (t == 1023) bsum[blockIdx.x] = s[1023];
}

__global__ void k_scan2(const int* __restrict__ bsum, int* __restrict__ bsumx,
                        int* __restrict__ h2) {
    __shared__ int s[512];
    int t = threadIdx.x;
    int v = (t < HSZ / 1024) ? bsum[t] : 0;
    s[t] = v;
    __syncthreads();
    for (int off = 1; off < 512; off <<= 1) {
        int u = (t >= off) ? s[t - off] : 0;
        __syncthreads();
        s[t] += u;
        __syncthreads();
    }
    if (t < HSZ / 1024) bsumx[t] = s[t] - v;
    if (t == 0) h2[HSZ] = N_EDGES;
}

__global__ void k_scan3(int* __restrict__ h2, const int* __restrict__ bsumx) {
    int i = blockIdx.x * 1024 + threadIdx.x;
    h2[i] += bsumx[blockIdx.x];
}

__global__ __launch_bounds__(256) void k_scatter(const int* __restrict__ src,
                                                 const int* __restrict__ dst,
                                                 const int* __restrict__ h2,
                                                 unsigned* __restrict__ pairs) {
    __shared__ int cur[NBKT];
    int t = threadIdx.x, b = blockIdx.x;
    for (int i = t; i < NBKT; i += 256) cur[i] = h2[i * NB + b];
    __syncthreads();
    int e0 = b * EPB;
    for (int e = e0 + t; e < e0 + EPB; e += 256) {
        int d = dst[e];
        int pos = atomicAdd(&cur[d >> 8], 1);
        pairs[pos] = ((unsigned)(d & 255) << 24) | (unsigned)src[e];
    }
}

// per bucket -> node-exact csr SORTED BY SOURCE RANGE within each node,
// roff (node base) + roffpk (packed u64: 8 per-range byte counts)
__global__ __launch_bounds__(256) void k_csr(const unsigned* __restrict__ pairs,
                                             const int* __restrict__ h2,
                                             int* __restrict__ roff,
                                             u64* __restrict__ roffpk,
                                             int* __restrict__ csr) {
    __shared__ int hist[2048];   // (dst_local<<3)|src_range ; reused as cursors
    __shared__ int tsum[256];
    int b = blockIdx.x;
    int e0 = h2[b * NB], e1 = h2[(b + 1) * NB];
    int t = threadIdx.x;
    for (int i = t; i < 2048; i += 256) hist[i] = 0;
    __syncthreads();
    for (int p = e0 + t; p < e1; p += 256) {
        unsigned pk = pairs[p];
        int sv = (int)(pk & 0xFFFFFF);
        int key = (int)((pk >> 24) << 3) | (sv / RNG);
        atomicAdd(&hist[key], 1);
    }
    __syncthreads();
    int c[8];
    int sum = 0;
    u64 pkc = 0;
    #pragma unroll
    for (int r = 0; r < 8; ++r) {
        c[r] = hist[t * 8 + r];
        pkc |= (u64)(unsigned)c[r] << (8 * r);
        sum += c[r];
    }
    roffpk[(b << 8) + t] = pkc;
    tsum[t] = sum;
    __syncthreads();
    for (int off = 1; off < 256; off <<= 1) {
        int u = (t >= off) ? tsum[t - off] : 0;
        __syncthreads();
        tsum[t] += u;
        __syncthreads();
    }
    int base = e0 + tsum[t] - sum;   // exclusive over nodes
    roff[(b << 8) + t] = base;
    if (b == 0 && t == 0) roff[N_NODES] = N_EDGES;
    int run = base;
    #pragma unroll
    for (int r = 0; r < 8; ++r) { int cc = c[r]; hist[t * 8 + r] = run; run += cc; }
    __syncthreads();
    for (int p = e0 + t; p < e1; p += 256) {
        unsigned pk = pairs[p];
        int sv = (int)(pk & 0xFFFFFF);
        int key = (int)((pk >> 24) << 3) | (sv / RNG);
        int pos = atomicAdd(&hist[key], 1);
        csr[pos] = sv;
    }
}

// ---------------- weight conversion to fp16 ----------------

__global__ void k_wcvt(const float* __restrict__ Wroot, const float* __restrict__ Wrel,
                       const float* __restrict__ Wres, const float* __restrict__ Win,
                       f16* __restrict__ W2h, f16* __restrict__ Wresh, f16* __restrict__ Winh) {
    int i = blockIdx.x * 256 + threadIdx.x;
    if (i < 4 * 64 * 128) {
        int l = i >> 13, r = i & 8191, j = r >> 7, k = r & 127;
        float v = (k < 64) ? Wroot[l * 4096 + j * 64 + k] : Wrel[l * 4096 + j * 64 + k - 64];
        W2h[i] = (f16)v;
    } else if (i < 4 * 64 * 128 + 4096) {
        int t = i - 4 * 64 * 128;
        Wresh[t] = (f16)Wres[t];
    } else if (i < 4 * 64 * 128 + 4096 + 2048) {
        int t = i - (4 * 64 * 128 + 4096);
        int j = t >> 5, k = t & 31;
        Winh[t] = (k < 9) ? (f16)Win[j * 9 + k] : (f16)0.f;
    }
}

// ---------------- input projection + residual via MFMA ----------------

__global__ __launch_bounds__(256) void k_proj(
        const float* __restrict__ x, const f16* __restrict__ Winh,
        const float* __restrict__ bin, const f16* __restrict__ Wresh,
        const float* __restrict__ bres, f16* __restrict__ h0,
        f16* __restrict__ res) {
    __shared__ f16 hs[4][16][64];
    int tid = threadIdx.x, w = tid >> 6, lane = tid & 63, li = lane & 15, kg = lane >> 4;
    int nb = blockIdx.x * 64 + w * 16;
    int node = nb + li;

    half8 ax;
    #pragma unroll
    for (int e = 0; e < 8; ++e) ax[e] = (f16)0.f;
    if (kg == 0) {
        #pragma unroll
        for (int e = 0; e < 8; ++e) ax[e] = (f16)x[(size_t)node * 9 + e];
    } else if (kg == 1) {
        ax[0] = (f16)x[(size_t)node * 9 + 8];
    }

    f32x4 ch[4];
    #pragma unroll
    for (int jt = 0; jt < 4; ++jt) {
        half8 b = *(const half8*)(Winh + (jt * 16 + li) * 32 + kg * 8);
        f32x4 z = {0.f, 0.f, 0.f, 0.f};
        ch[jt] = mfma16(ax, b, z);
    }
    #pragma unroll
    for (int jt = 0; jt < 4; ++jt) {
        float bb = bin[jt * 16 + li];
        #pragma unroll
        for (int r = 0; r < 4; ++r) {
            int row = kg * 4 + r;
            float v = ch[jt][r] + bb;
            f16 hv = (f16)v;
            h0[(size_t)(nb + row) * 64 + jt * 16 + li] = hv;
            int col = jt * 16 + li;
            hs[w][row][col ^ ((row & 7) * 8)] = hv;
        }
    }
    __syncthreads();

    f32x4 cr[4];
    #pragma unroll
    for (int jt = 0; jt < 4; ++jt) { f32x4 z = {0.f,0.f,0.f,0.f}; cr[jt] = z; }
    #pragma unroll
    for (int s = 0; s < 2; ++s) {
        int k0 = s * 32 + kg * 8;
        half8 a = *(const half8*)(&hs[w][li][k0 ^ ((li & 7) * 8)]);
        #pragma unroll
        for (int jt = 0; jt < 4; ++jt) {
            half8 b = *(const half8*)(Wresh + (jt * 16 + li) * 64 + k0);
            cr[jt] = mfma16(a, b, cr[jt]);
        }
    }
    #pragma unroll
    for (int jt = 0; jt < 4; ++jt) {
        float bb = bres[jt * 16 + li];
        #pragma unroll
        for (int r = 0; r < 4; ++r)
            res[(size_t)(nb + kg * 4 + r) * 64 + jt * 16 + li] = (f16)(cr[jt][r] + bb);
    }
}

// ---------------- fused layer: range-major L2-resident gather -> LDS -> MFMA ----------------
// block = 64 nodes, 4 waves, 2592 blocks (R9 structure). 8-lane group owns 2 nodes;
// edges per node sorted by src range; ranges processed outermost for L2 locality.

__global__ __launch_bounds__(256) void k_layer(
        const f16* __restrict__ h, const f16* __restrict__ res,
        const int* __restrict__ roff, const u64* __restrict__ roffpk,
        const int* __restrict__ csr,
        const f16* __restrict__ W2h, const float* __restrict__ bconv,
        const float* __restrict__ lng, const float* __restrict__ lnb,
        f16* __restrict__ hn) {
    __shared__ f16 hs[4][16][64];
    int tid = threadIdx.x, lane = tid & 63, w = tid >> 6;
    int g = lane >> 3, s = lane & 7;
    int blk = blockIdx.x;

    int nb16 = blk * 64 + w * 16;
    int n0 = nb16 + g, n1 = nb16 + 8 + g;
    int cur0 = roff[n0], cur1 = roff[n1];
    u64 pk0 = roffpk[n0], pk1 = roffpk[n1];

    float A0[8], A1[8];
    #pragma unroll
    for (int j = 0; j < 8; ++j) { A0[j] = 0.f; A1[j] = 0.f; }

    for (int r = 0; r < 8; ++r) {
        int c0 = (int)((pk0 >> (8 * r)) & 255);
        int c1 = (int)((pk1 >> (8 * r)) & 255);
        int end0 = cur0 + c0, end1 = cur1 + c1;
        // node 0, range r
        for (; cur0 + 3 < end0; cur0 += 4) {
            half8 v0 = *(const half8*)(h + ((size_t)csr[cur0]     << 6) + s * 8);
            half8 v1 = *(const half8*)(h + ((size_t)csr[cur0 + 1] << 6) + s * 8);
            half8 v2 = *(const half8*)(h + ((size_t)csr[cur0 + 2] << 6) + s * 8);
            half8 v3 = *(const half8*)(h + ((size_t)csr[cur0 + 3] << 6) + s * 8);
            #pragma unroll
            for (int j = 0; j < 8; ++j)
                A0[j] += ((float)v0[j] + (float)v1[j]) + ((float)v2[j] + (float)v3[j]);
        }
        for (; cur0 < end0; ++cur0) {
            half8 v0 = *(const half8*)(h + ((size_t)csr[cur0] << 6) + s * 8);
            #pragma unroll
            for (int j = 0; j < 8; ++j) A0[j] += (float)v0[j];
        }
        // node 1, range r
        for (; cur1 + 3 < end1; cur1 += 4) {
            half8 v0 = *(const half8*)(h + ((size_t)csr[cur1]     << 6) + s * 8);
            half8 v1 = *(const half8*)(h + ((size_t)csr[cur1 + 1] << 6) + s * 8);
            half8 v2 = *(const half8*)(h + ((size_t)csr[cur1 + 2] << 6) + s * 8);
            half8 v3 = *(const half8*)(h + ((size_t)csr[cur1 + 3] << 6) + s * 8);
            #pragma unroll
            for (int j = 0; j < 8; ++j)
                A1[j] += ((float)v0[j] + (float)v1[j]) + ((float)v2[j] + (float)v3[j]);
        }
        for (; cur1 < end1; ++cur1) {
            half8 v0 = *(const half8*)(h + ((size_t)csr[cur1] << 6) + s * 8);
            #pragma unroll
            for (int j = 0; j < 8; ++j) A1[j] += (float)v0[j];
        }
    }

    half8 o0, o1;
    #pragma unroll
    for (int j = 0; j < 8; ++j) { o0[j] = (f16)A0[j]; o1[j] = (f16)A1[j]; }
    *(half8*)(&hs[w][g][(s ^ (g & 7)) * 8]) = o0;
    *(half8*)(&hs[w][8 + g][(s ^ (g & 7)) * 8]) = o1;   // (8+g)&7 == g&7
    // no __syncthreads(): each wave reads only rows it wrote

    // ---- update phase: wave w -> 16-node MFMA tile ----
    int li = lane & 15, kg = lane >> 4;
    int node = nb16 + li;

    f32x4 C[4];
    #pragma unroll
    for (int jt = 0; jt < 4; ++jt) { f32x4 z = {0.f,0.f,0.f,0.f}; C[jt] = z; }

    #pragma unroll
    for (int st = 0; st < 4; ++st) {
        half8 a;
        if (st < 2) {
            a = *(const half8*)(h + ((size_t)node << 6) + st * 32 + kg * 8);
        } else {
            int m = (st - 2) * 4 + kg;
            a = *(const half8*)(&hs[w][li][(m ^ (li & 7)) * 8]);
        }
        #pragma unroll
        for (int jt = 0; jt < 4; ++jt) {
            half8 b = *(const half8*)(W2h + (size_t)(jt * 16 + li) * 128 + st * 32 + kg * 8);
            C[jt] = mfma16(a, b, C[jt]);
        }
    }

    #pragma unroll
    for (int jt = 0; jt < 4; ++jt) {
        float bb = bconv[jt * 16 + li];
        #pragma unroll
        for (int r = 0; r < 4; ++r) C[jt][r] += bb;
    }

    float mu[4], rstd[4];
    #pragma unroll
    for (int r = 0; r < 4; ++r) {
        float v = C[0][r] + C[1][r] + C[2][r] + C[3][r];
        v += __shfl_xor(v, 1, 64); v += __shfl_xor(v, 2, 64);
        v += __shfl_xor(v, 4, 64); v += __shfl_xor(v, 8, 64);
        mu[r] = v * (1.f / 64.f);
    }
    #pragma unroll
    for (int r = 0; r < 4; ++r) {
        float d0 = C[0][r] - mu[r], d1 = C[1][r] - mu[r];
        float d2 = C[2][r] - mu[r], d3 = C[3][r] - mu[r];
        float vv = d0 * d0 + d1 * d1 + d2 * d2 + d3 * d3;
        vv += __shfl_xor(vv, 1, 64); vv += __shfl_xor(vv, 2, 64);
        vv += __shfl_xor(vv, 4, 64); vv += __shfl_xor(vv, 8, 64);
        rstd[r] = rsqrtf(vv * (1.f / 64.f) + LN_EPS);
    }
    #pragma unroll
    for (int jt = 0; jt < 4; ++jt) {
        float gg = lng[jt * 16 + li], bb = lnb[jt * 16 + li];
        #pragma unroll
        for (int r = 0; r < 4; ++r) {
            size_t idx = (size_t)(nb16 + kg * 4 + r) * 64 + jt * 16 + li;
            float y = (C[jt][r] - mu[r]) * rstd[r] * gg + bb;
            y = (y > 0.f) ? y : 0.01f * y;
            y += (float)res[idx];
            hn[idx] = (f16)y;
        }
    }
}

// ---------------- output projection: node per lane ----------------

__global__ __launch_bounds__(256) void k_out(
        const f16* __restrict__ h, const float* __restrict__ Wout,
        const float* __restrict__ bout, float* __restrict__ out) {
    int node = blockIdx.x * 256 + threadIdx.x;
    float acc[9];
    #pragma unroll
    for (int c = 0; c < 9; ++c) acc[c] = bout[c];
    #pragma unroll
    for (int cc = 0; cc < 8; ++cc) {
        half8 v = *(const half8*)(h + ((size_t)node << 6) + cc * 8);
        float f[8];
        #pragma unroll
        for (int e = 0; e < 8; ++e) f[e] = (float)v[e];
        #pragma unroll
        for (int c = 0; c < 9; ++c) {
            #pragma unroll
            for (int e = 0; e < 8; ++e)
                acc[c] += f[e] * Wout[c * 64 + cc * 8 + e];
        }
    }
    #pragma unroll
    for (int c = 0; c < 9; ++c) out[(size_t)node * 9 + c] = acc[c];
}

extern "C" void kernel_launch(void* const* d_in, const int* in_sizes, int n_in,
                              void* d_out, int out_size, void* d_ws, size_t ws_size,
                              hipStream_t stream) {
    const float* x     = (const float*)d_in[0];
    const int*   ei    = (const int*)d_in[1];
    const float* Win   = (const float*)d_in[2];
    const float* bin   = (const float*)d_in[3];
    const float* Wrel  = (const float*)d_in[4];
    const float* Wroot = (const float*)d_in[5];
    const float* bconv = (const float*)d_in[6];
    const float* Wres  = (const float*)d_in[7];
    const float* bres  = (const float*)d_in[8];
    const float* lng   = (const float*)d_in[9];
    const float* lnb   = (const float*)d_in[10];
    const float* Wout  = (const float*)d_in[11];
    const float* bout  = (const float*)d_in[12];
    float* out = (float*)d_out;

    char* p = (char*)d_ws;
    auto alloc = [&](size_t bytes) {
        char* r = p;
        p += (bytes + 255) & ~(size_t)255;
        return r;
    };
    f16*      h0     = (f16*)alloc((size_t)N_NODES * 64 * 2);
    f16*      h1     = (f16*)alloc((size_t)N_NODES * 64 * 2);
    f16*      res    = (f16*)alloc((size_t)N_NODES * 64 * 2);
    unsigned* pairs  = (unsigned*)alloc((size_t)N_EDGES * 4);
    int*      csr    = (int*)alloc((size_t)N_EDGES * 4);
    int*      roff   = (int*)alloc((size_t)(N_NODES + 1) * 4);
    u64*      roffpk = (u64*)alloc((size_t)N_NODES * 8);
    int*      h2     = (int*)alloc((size_t)(HSZ + 1) * 4);
    int*      bsum   = (int*)alloc((HSZ / 1024) * 4);
    int*      bsumx  = (int*)alloc((HSZ / 1024) * 4);
    f16*      W2h    = (f16*)alloc(4 * 64 * 128 * 2);
    f16*      Wresh  = (f16*)alloc(64 * 64 * 2);
    f16*      Winh   = (f16*)alloc(64 * 32 * 2);

    const int* srcv = ei;
    const int* dstv = ei + N_EDGES;

    k_hist2d<<<NB, 256, 0, stream>>>(dstv, h2);
    k_scan1<<<HSZ / 1024, 1024, 0, stream>>>(h2, bsum);
    k_scan2<<<1, 512, 0, stream>>>(bsum, bsumx, h2);
    k_scan3<<<HSZ / 1024, 1024, 0, stream>>>(h2, bsumx);
    k_scatter<<<NB, 256, 0, stream>>>(srcv, dstv, h2, pairs);
    k_csr<<<NBKT, 256, 0, stream>>>(pairs, h2, roff, roffpk, csr);

    k_wcvt<<<152, 256, 0, stream>>>(Wroot, Wrel, Wres, Win, W2h, Wresh, Winh);
    k_proj<<<N_NODES / 64, 256, 0, stream>>>(x, Winh, bin, Wresh, bres, h0, res);

    f16* ha = h0;
    f16* hb = h1;
    for (int l = 0; l < 4; ++l) {
        k_layer<<<N_NODES / 64, 256, 0, stream>>>(ha, res, roff, roffpk, csr,
                                                  W2h + (size_t)l * 64 * 128,
                                                  bconv + l * 64, lng, lnb, hb);
        f16* t = ha; ha = hb; hb = t;
    }
    k_out<<<N_NODES / 256, 256, 0, stream>>>(ha, Wout, bout, out);
}

// Round 12
// 442.491 us; speedup vs baseline: 1.5586x; 1.5586x over previous
//
#include <hip/hip_runtime.h>

#define N_NODES 165888
#define N_EDGES 3317760
#define NBKT 648            // N_NODES >> 8 buckets (256 nodes each)
#define NB 512              // partition blocks
#define EPB (N_EDGES / NB)  // 6480 edges per partition block
#define HSZ (NBKT * NB)     // 331776 counters
#define RNG 20736           // N_NODES / 8 : source-range width for sort key
#define LN_EPS 1e-5f

typedef _Float16 f16;
typedef _Float16 half8 __attribute__((ext_vector_type(8)));
typedef float f32x4 __attribute__((ext_vector_type(4)));

__device__ __forceinline__ f32x4 mfma16(half8 a, half8 b, f32x4 c) {
    return __builtin_amdgcn_mfma_f32_16x16x32_f16(a, b, c, 0, 0, 0);
}

// ---------------- radix partition (no global atomics, no contention) ----------------

__global__ __launch_bounds__(256) void k_hist2d(const int* __restrict__ dst,
                                                int* __restrict__ h2) {
    __shared__ int hist[NBKT];
    int t = threadIdx.x, b = blockIdx.x;
    for (int i = t; i < NBKT; i += 256) hist[i] = 0;
    __syncthreads();
    int e0 = b * EPB;
    for (int e = e0 + t; e < e0 + EPB; e += 256)
        atomicAdd(&hist[dst[e] >> 8], 1);
    __syncthreads();
    for (int i = t; i < NBKT; i += 256)
        h2[i * NB + b] = hist[i];
}

__global__ void k_scan1(int* __restrict__ h2, int* __restrict__ bsum) {
    __shared__ int s[1024];
    int t = threadIdx.x;
    int i = blockIdx.x * 1024 + t;
    int own = h2[i];
    s[t] = own;
    __syncthreads();
    for (int off = 1; off < 1024; off <<= 1) {
        int u = (t >= off) ? s[t - off] : 0;
        __syncthreads();
        s[t] += u;
        __syncthreads();
    }
    h2[i] = s[t] - own;
    if (t == 1023) bsum[blockIdx.x] = s[1023];
}

__global__ void k_scan2(const int* __restrict__ bsum, int* __restrict__ bsumx,
                        int* __restrict__ h2) {
    __shared__ int s[512];
    int t = threadIdx.x;
    int v = (t < HSZ / 1024) ? bsum[t] : 0;
    s[t] = v;
    __syncthreads();
    for (int off = 1; off < 512; off <<= 1) {
        int u = (t >= off) ? s[t - off] : 0;
        __syncthreads();
        s[t] += u;
        __syncthreads();
    }
    if (t < HSZ / 1024) bsumx[t] = s[t] - v;
    if (t == 0) h2[HSZ] = N_EDGES;
}

__global__ void k_scan3(int* __restrict__ h2, const int* __restrict__ bsumx) {
    int i = blockIdx.x * 1024 + threadIdx.x;
    h2[i] += bsumx[blockIdx.x];
}

__global__ __launch_bounds__(256) void k_scatter(const int* __restrict__ src,
                                                 const int* __restrict__ dst,
                                                 const int* __restrict__ h2,
                                                 unsigned* __restrict__ pairs) {
    __shared__ int cur[NBKT];
    int t = threadIdx.x, b = blockIdx.x;
    for (int i = t; i < NBKT; i += 256) cur[i] = h2[i * NB + b];
    __syncthreads();
    int e0 = b * EPB;
    for (int e = e0 + t; e < e0 + EPB; e += 256) {
        int d = dst[e];
        int pos = atomicAdd(&cur[d >> 8], 1);
        pairs[pos] = ((unsigned)(d & 255) << 24) | (unsigned)src[e];
    }
}

// per bucket -> node-exact csr, SORTED BY SOURCE RANGE within each node.
// (sorted storage order is the only change vs the proven R9 build; the
//  layer kernel walks lists straight through, getting a chip-wide sliding
//  source window for L2 locality.)
__global__ __launch_bounds__(256) void k_csr(const unsigned* __restrict__ pairs,
                                             const int* __restrict__ h2,
                                             int* __restrict__ roff,
                                             int* __restrict__ csr) {
    __shared__ int hist[2048];   // (dst_local<<3)|src_range ; reused as cursors
    __shared__ int tsum[256];
    int b = blockIdx.x;
    int e0 = h2[b * NB], e1 = h2[(b + 1) * NB];
    int t = threadIdx.x;
    for (int i = t; i < 2048; i += 256) hist[i] = 0;
    __syncthreads();
    for (int p = e0 + t; p < e1; p += 256) {
        unsigned pk = pairs[p];
        int sv = (int)(pk & 0xFFFFFF);
        int key = (int)((pk >> 24) << 3) | (sv / RNG);
        atomicAdd(&hist[key], 1);
    }
    __syncthreads();
    int c[8];
    int sum = 0;
    #pragma unroll
    for (int r = 0; r < 8; ++r) { c[r] = hist[t * 8 + r]; sum += c[r]; }
    tsum[t] = sum;
    __syncthreads();
    for (int off = 1; off < 256; off <<= 1) {
        int u = (t >= off) ? tsum[t - off] : 0;
        __syncthreads();
        tsum[t] += u;
        __syncthreads();
    }
    int base = e0 + tsum[t] - sum;   // exclusive over nodes
    roff[(b << 8) + t] = base;
    if (b == 0 && t == 0) roff[N_NODES] = N_EDGES;
    int run = base;
    #pragma unroll
    for (int r = 0; r < 8; ++r) { int cc = c[r]; hist[t * 8 + r] = run; run += cc; }
    __syncthreads();
    for (int p = e0 + t; p < e1; p += 256) {
        unsigned pk = pairs[p];
        int sv = (int)(pk & 0xFFFFFF);
        int key = (int)((pk >> 24) << 3) | (sv / RNG);
        int pos = atomicAdd(&hist[key], 1);
        csr[pos] = sv;
    }
}

// ---------------- weight conversion to fp16 ----------------

__global__ void k_wcvt(const float* __restrict__ Wroot, const float* __restrict__ Wrel,
                       const float* __restrict__ Wres, const float* __restrict__ Win,
                       f16* __restrict__ W2h, f16* __restrict__ Wresh, f16* __restrict__ Winh) {
    int i = blockIdx.x * 256 + threadIdx.x;
    if (i < 4 * 64 * 128) {
        int l = i >> 13, r = i & 8191, j = r >> 7, k = r & 127;
        float v = (k < 64) ? Wroot[l * 4096 + j * 64 + k] : Wrel[l * 4096 + j * 64 + k - 64];
        W2h[i] = (f16)v;
    } else if (i < 4 * 64 * 128 + 4096) {
        int t = i - 4 * 64 * 128;
        Wresh[t] = (f16)Wres[t];
    } else if (i < 4 * 64 * 128 + 4096 + 2048) {
        int t = i - (4 * 64 * 128 + 4096);
        int j = t >> 5, k = t & 31;
        Winh[t] = (k < 9) ? (f16)Win[j * 9 + k] : (f16)0.f;
    }
}

// ---------------- input projection + residual via MFMA ----------------

__global__ __launch_bounds__(256) void k_proj(
        const float* __restrict__ x, const f16* __restrict__ Winh,
        const float* __restrict__ bin, const f16* __restrict__ Wresh,
        const float* __restrict__ bres, f16* __restrict__ h0,
        f16* __restrict__ res) {
    __shared__ f16 hs[4][16][64];
    int tid = threadIdx.x, w = tid >> 6, lane = tid & 63, li = lane & 15, kg = lane >> 4;
    int nb = blockIdx.x * 64 + w * 16;
    int node = nb + li;

    half8 ax;
    #pragma unroll
    for (int e = 0; e < 8; ++e) ax[e] = (f16)0.f;
    if (kg == 0) {
        #pragma unroll
        for (int e = 0; e < 8; ++e) ax[e] = (f16)x[(size_t)node * 9 + e];
    } else if (kg == 1) {
        ax[0] = (f16)x[(size_t)node * 9 + 8];
    }

    f32x4 ch[4];
    #pragma unroll
    for (int jt = 0; jt < 4; ++jt) {
        half8 b = *(const half8*)(Winh + (jt * 16 + li) * 32 + kg * 8);
        f32x4 z = {0.f, 0.f, 0.f, 0.f};
        ch[jt] = mfma16(ax, b, z);
    }
    #pragma unroll
    for (int jt = 0; jt < 4; ++jt) {
        float bb = bin[jt * 16 + li];
        #pragma unroll
        for (int r = 0; r < 4; ++r) {
            int row = kg * 4 + r;
            float v = ch[jt][r] + bb;
            f16 hv = (f16)v;
            h0[(size_t)(nb + row) * 64 + jt * 16 + li] = hv;
            int col = jt * 16 + li;
            hs[w][row][col ^ ((row & 7) * 8)] = hv;
        }
    }
    __syncthreads();

    f32x4 cr[4];
    #pragma unroll
    for (int jt = 0; jt < 4; ++jt) { f32x4 z = {0.f,0.f,0.f,0.f}; cr[jt] = z; }
    #pragma unroll
    for (int s = 0; s < 2; ++s) {
        int k0 = s * 32 + kg * 8;
        half8 a = *(const half8*)(&hs[w][li][k0 ^ ((li & 7) * 8)]);
        #pragma unroll
        for (int jt = 0; jt < 4; ++jt) {
            half8 b = *(const half8*)(Wresh + (jt * 16 + li) * 64 + k0);
            cr[jt] = mfma16(a, b, cr[jt]);
        }
    }
    #pragma unroll
    for (int jt = 0; jt < 4; ++jt) {
        float bb = bres[jt * 16 + li];
        #pragma unroll
        for (int r = 0; r < 4; ++r)
            res[(size_t)(nb + kg * 4 + r) * 64 + jt * 16 + li] = (f16)(cr[jt][r] + bb);
    }
}

// ---------------- fused layer: EXACT R9 structure (src-sorted csr gives locality) ----------------

__global__ __launch_bounds__(256) void k_layer(
        const f16* __restrict__ h, const f16* __restrict__ res,
        const int* __restrict__ roff, const int* __restrict__ csr,
        const f16* __restrict__ W2h, const float* __restrict__ bconv,
        const float* __restrict__ lng, const float* __restrict__ lnb,
        f16* __restrict__ hn) {
    __shared__ f16 hs[4][16][64];
    int tid = threadIdx.x, lane = tid & 63, w = tid >> 6;
    int g = lane >> 3, s = lane & 7;
    int blk = blockIdx.x;

    // ---- gather phase: 2 rounds x 8 groups = 16 nodes per wave ----
    #pragma unroll
    for (int r2 = 0; r2 < 2; ++r2) {
        int nl = r2 * 8 + g;                  // 0..15 within wave
        int n = blk * 64 + w * 16 + nl;
        int e0 = roff[n], e1 = roff[n + 1];
        float a[8];
        #pragma unroll
        for (int j = 0; j < 8; ++j) a[j] = 0.f;

        int p = e0;
        for (; p + 7 < e1; p += 8) {
            half8 v[8];
            #pragma unroll
            for (int q = 0; q < 8; ++q) {
                int idx = csr[p + q];
                v[q] = *(const half8*)(h + ((size_t)idx << 6) + s * 8);
            }
            #pragma unroll
            for (int q = 0; q < 8; ++q) {
                #pragma unroll
                for (int j = 0; j < 8; ++j) a[j] += (float)v[q][j];
            }
        }
        for (; p + 3 < e1; p += 4) {
            half8 v[4];
            #pragma unroll
            for (int q = 0; q < 4; ++q) {
                int idx = csr[p + q];
                v[q] = *(const half8*)(h + ((size_t)idx << 6) + s * 8);
            }
            #pragma unroll
            for (int q = 0; q < 4; ++q) {
                #pragma unroll
                for (int j = 0; j < 8; ++j) a[j] += (float)v[q][j];
            }
        }
        for (; p < e1; ++p) {
            int idx = csr[p];
            half8 v0 = *(const half8*)(h + ((size_t)idx << 6) + s * 8);
            #pragma unroll
            for (int j = 0; j < 8; ++j) a[j] += (float)v0[j];
        }

        half8 o;
        #pragma unroll
        for (int j = 0; j < 8; ++j) o[j] = (f16)a[j];
        *(half8*)(&hs[w][nl][(s ^ (nl & 7)) * 8]) = o;   // swizzled row write
    }
    // no __syncthreads(): each wave reads only rows it wrote

    // ---- update phase: wave w -> 16-node MFMA tile ----
    int li = lane & 15, kg = lane >> 4;
    int nb = blk * 64 + w * 16;
    int node = nb + li;

    f32x4 C[4];
    #pragma unroll
    for (int jt = 0; jt < 4; ++jt) { f32x4 z = {0.f,0.f,0.f,0.f}; C[jt] = z; }

    #pragma unroll
    for (int st = 0; st < 4; ++st) {
        half8 a;
        if (st < 2) {
            a = *(const half8*)(h + ((size_t)node << 6) + st * 32 + kg * 8);
        } else {
            int m = (st - 2) * 4 + kg;         // 8-elem chunk index 0..7
            a = *(const half8*)(&hs[w][li][(m ^ (li & 7)) * 8]);
        }
        #pragma unroll
        for (int jt = 0; jt < 4; ++jt) {
            half8 b = *(const half8*)(W2h + (size_t)(jt * 16 + li) * 128 + st * 32 + kg * 8);
            C[jt] = mfma16(a, b, C[jt]);
        }
    }

    #pragma unroll
    for (int jt = 0; jt < 4; ++jt) {
        float bb = bconv[jt * 16 + li];
        #pragma unroll
        for (int r = 0; r < 4; ++r) C[jt][r] += bb;
    }

    float mu[4], rstd[4];
    #pragma unroll
    for (int r = 0; r < 4; ++r) {
        float v = C[0][r] + C[1][r] + C[2][r] + C[3][r];
        v += __shfl_xor(v, 1, 64); v += __shfl_xor(v, 2, 64);
        v += __shfl_xor(v, 4, 64); v += __shfl_xor(v, 8, 64);
        mu[r] = v * (1.f / 64.f);
    }
    #pragma unroll
    for (int r = 0; r < 4; ++r) {
        float d0 = C[0][r] - mu[r], d1 = C[1][r] - mu[r];
        float d2 = C[2][r] - mu[r], d3 = C[3][r] - mu[r];
        float vv = d0 * d0 + d1 * d1 + d2 * d2 + d3 * d3;
        vv += __shfl_xor(vv, 1, 64); vv += __shfl_xor(vv, 2, 64);
        vv += __shfl_xor(vv, 4, 64); vv += __shfl_xor(vv, 8, 64);
        rstd[r] = rsqrtf(vv * (1.f / 64.f) + LN_EPS);
    }
    #pragma unroll
    for (int jt = 0; jt < 4; ++jt) {
        float gg = lng[jt * 16 + li], bb = lnb[jt * 16 + li];
        #pragma unroll
        for (int r = 0; r < 4; ++r) {
            size_t idx = (size_t)(nb + kg * 4 + r) * 64 + jt * 16 + li;
            float y = (C[jt][r] - mu[r]) * rstd[r] * gg + bb;
            y = (y > 0.f) ? y : 0.01f * y;
            y += (float)res[idx];
            hn[idx] = (f16)y;
        }
    }
}

// ---------------- output projection: node per lane ----------------

__global__ __launch_bounds__(256) void k_out(
        const f16* __restrict__ h, const float* __restrict__ Wout,
        const float* __restrict__ bout, float* __restrict__ out) {
    int node = blockIdx.x * 256 + threadIdx.x;
    float acc[9];
    #pragma unroll
    for (int c = 0; c < 9; ++c) acc[c] = bout[c];
    #pragma unroll
    for (int cc = 0; cc < 8; ++cc) {
        half8 v = *(const half8*)(h + ((size_t)node << 6) + cc * 8);
        float f[8];
        #pragma unroll
        for (int e = 0; e < 8; ++e) f[e] = (float)v[e];
        #pragma unroll
        for (int c = 0; c < 9; ++c) {
            #pragma unroll
            for (int e = 0; e < 8; ++e)
                acc[c] += f[e] * Wout[c * 64 + cc * 8 + e];
        }
    }
    #pragma unroll
    for (int c = 0; c < 9; ++c) out[(size_t)node * 9 + c] = acc[c];
}

extern "C" void kernel_launch(void* const* d_in, const int* in_sizes, int n_in,
                              void* d_out, int out_size, void* d_ws, size_t ws_size,
                              hipStream_t stream) {
    const float* x     = (const float*)d_in[0];
    const int*   ei    = (const int*)d_in[1];
    const float* Win   = (const float*)d_in[2];
    const float* bin   = (const float*)d_in[3];
    const float* Wrel  = (const float*)d_in[4];
    const float* Wroot = (const float*)d_in[5];
    const float* bconv = (const float*)d_in[6];
    const float* Wres  = (const float*)d_in[7];
    const float* bres  = (const float*)d_in[8];
    const float* lng   = (const float*)d_in[9];
    const float* lnb   = (const float*)d_in[10];
    const float* Wout  = (const float*)d_in[11];
    const float* bout  = (const float*)d_in[12];
    float* out = (float*)d_out;

    char* p = (char*)d_ws;
    auto alloc = [&](size_t bytes) {
        char* r = p;
        p += (bytes + 255) & ~(size_t)255;
        return r;
    };
    f16*      h0    = (f16*)alloc((size_t)N_NODES * 64 * 2);
    f16*      h1    = (f16*)alloc((size_t)N_NODES * 64 * 2);
    f16*      res   = (f16*)alloc((size_t)N_NODES * 64 * 2);
    unsigned* pairs = (unsigned*)alloc((size_t)N_EDGES * 4);
    int*      csr   = (int*)alloc((size_t)N_EDGES * 4);
    int*      roff  = (int*)alloc((size_t)(N_NODES + 1) * 4);
    int*      h2    = (int*)alloc((size_t)(HSZ + 1) * 4);
    int*      bsum  = (int*)alloc((HSZ / 1024) * 4);
    int*      bsumx = (int*)alloc((HSZ / 1024) * 4);
    f16*      W2h   = (f16*)alloc(4 * 64 * 128 * 2);
    f16*      Wresh = (f16*)alloc(64 * 64 * 2);
    f16*      Winh  = (f16*)alloc(64 * 32 * 2);

    const int* srcv = ei;
    const int* dstv = ei + N_EDGES;

    k_hist2d<<<NB, 256, 0, stream>>>(dstv, h2);
    k_scan1<<<HSZ / 1024, 1024, 0, stream>>>(h2, bsum);
    k_scan2<<<1, 512, 0, stream>>>(bsum, bsumx, h2);
    k_scan3<<<HSZ / 1024, 1024, 0, stream>>>(h2, bsumx);
    k_scatter<<<NB, 256, 0, stream>>>(srcv, dstv, h2, pairs);
    k_csr<<<NBKT, 256, 0, stream>>>(pairs, h2, roff, csr);

    k_wcvt<<<152, 256, 0, stream>>>(Wroot, Wrel, Wres, Win, W2h, Wresh, Winh);
    k_proj<<<N_NODES / 64, 256, 0, stream>>>(x, Winh, bin, Wresh, bres, h0, res);

    f16* ha = h0;
    f16* hb = h1;
    for (int l = 0; l < 4; ++l) {
        k_layer<<<N_NODES / 64, 256, 0, stream>>>(ha, res, roff, csr,
                                                  W2h + (size_t)l * 64 * 128,
                                                  bconv + l * 64, lng, lnb, hb);
        f16* t = ha; ha = hb; hb = t;
    }
    k_out<<<N_NODES / 256, 256, 0, stream>>>(ha, Wout, bout, out);
}